// Round 12
// baseline (729.212 us; speedup 1.0000x reference)
//
#include <hip/hip_runtime.h>
#include <hip/hip_bf16.h>
#include <math.h>

#define N_ENT   40000
#define N_REL2  480
#define D       128
#define T_STEPS 8
#define E_EDGES 200000
#define SQC     0.1f                 // sqrt(C), C = 0.01
#define RRELU_SLOPE 0.22916666666666666f
#define EPS_    1e-6f
#define NB      313                  // buckets = ceil(N_ENT/128), key = dst>>7

typedef _Float16 f16;
typedef _Float16 f16x8 __attribute__((ext_vector_type(8)));
typedef _Float16 f16x4 __attribute__((ext_vector_type(4)));
typedef _Float16 f16x2 __attribute__((ext_vector_type(2)));
typedef float    f32x4 __attribute__((ext_vector_type(4)));

// ---------------------------------------------------------------------------
// emb_rel16 = (f16) emb_rel
// ---------------------------------------------------------------------------
__global__ __launch_bounds__(256) void cvt_rel_kernel(const float* __restrict__ emb_rel,
                                                      f16* __restrict__ emb_rel16) {
    int i = blockIdx.x * blockDim.x + threadIdx.x;
    if (i < N_REL2 * D) emb_rel16[i] = (f16)emb_rel[i];
}

// ---------------------------------------------------------------------------
// Wpack: fragment-layout fp16 pack of {wn,wl,wg}.
// ---------------------------------------------------------------------------
__global__ __launch_bounds__(256) void cvtw_kernel(const float* __restrict__ wn,
                                                   const float* __restrict__ wl,
                                                   const float* __restrict__ wg,
                                                   f16* __restrict__ wpack) {
    int idx = blockIdx.x * blockDim.x + threadIdx.x;   // 0 .. 49151
    int j    = idx & 7;
    int lane = (idx >> 3) & 63;
    int ks   = (idx >> 9) & 3;
    int nt   = (idx >> 11) & 7;
    int g    = idx >> 14;
    const float* W = (g == 0) ? wn : (g == 1) ? wl : wg;
    int k = ks * 32 + (lane >> 4) * 8 + j;
    int n = nt * 16 + (lane & 15);
    wpack[idx] = (f16)W[k * D + n];
}

// ---------------------------------------------------------------------------
// logmap0 of initial h: h_tan (fp32) + h_tan16 (fp16)
// ---------------------------------------------------------------------------
__global__ __launch_bounds__(256) void logmap_kernel(const float* __restrict__ h,
                                                     float* __restrict__ h_tan,
                                                     f16* __restrict__ h_tan16) {
    int wid  = (blockIdx.x * blockDim.x + threadIdx.x) >> 6;
    int lane = threadIdx.x & 63;
    if (wid >= N_ENT) return;
    int base = wid * D + lane * 2;
    float2 hv = *reinterpret_cast<const float2*>(h + base);
    float ss = hv.x * hv.x + hv.y * hv.y;
    #pragma unroll
    for (int off = 32; off >= 1; off >>= 1) ss += __shfl_xor(ss, off, 64);
    float n = fmaxf(sqrtf(ss), EPS_);
    float t = fminf(SQC * n, 1.0f - 1e-5f);
    float scale = atanhf(t) / (SQC * n);
    float ox = hv.x * scale, oy = hv.y * scale;
    *reinterpret_cast<float2*>(h_tan + base) = make_float2(ox, oy);
    f16x2 o16 = {(f16)ox, (f16)oy};
    *reinterpret_cast<f16x2*>(h_tan16 + base) = o16;
}

// ---------------------------------------------------------------------------
// Pass A1: bucket histogram (LDS-chunked; 2048 edges/block)
// ---------------------------------------------------------------------------
__global__ __launch_bounds__(256) void bin_hist_kernel(const int* __restrict__ dst,
                                                       int* __restrict__ bhist) {
    __shared__ int lh[NB];
    int t = blockIdx.y, tid = threadIdx.x;
    for (int j = tid; j < NB; j += 256) lh[j] = 0;
    __syncthreads();
    int base = blockIdx.x * 2048;
    #pragma unroll
    for (int c = 0; c < 8; ++c) {
        int e = base + c * 256 + tid;
        if (e < E_EDGES) atomicAdd(&lh[dst[(size_t)t * E_EDGES + e] >> 7], 1);
    }
    __syncthreads();
    for (int j = tid; j < NB; j += 256)
        if (lh[j]) atomicAdd(&bhist[t * NB + j], lh[j]);
}

// ---------------------------------------------------------------------------
// Pass A2: exclusive scan of 313 bucket counts per step; init cursors;
// row_ptr[t][0] = 0
// ---------------------------------------------------------------------------
__global__ __launch_bounds__(512) void bin_scan_kernel(const int* __restrict__ bhist,
                                                       int* __restrict__ boffs,
                                                       int* __restrict__ bcur,
                                                       int* __restrict__ row_ptr) {
    __shared__ int s[512];
    int t = blockIdx.x, tid = threadIdx.x;
    int orig = (tid < NB) ? bhist[t * NB + tid] : 0;
    s[tid] = orig;
    __syncthreads();
    for (int off = 1; off < 512; off <<= 1) {
        int v = (tid >= off) ? s[tid - off] : 0;
        __syncthreads();
        s[tid] += v;
        __syncthreads();
    }
    if (tid < NB) {
        int excl = s[tid] - orig;
        boffs[t * NB + tid] = excl;
        bcur[t * NB + tid]  = excl;
    }
    if (tid == 0) row_ptr[t * (N_ENT + 1)] = 0;
}

// ---------------------------------------------------------------------------
// Pass A3: scatter edges into bucket-major array.
// payload = src | rel<<16 | (dst&127)<<25  (16+9+7 = 32 bits exactly)
// ---------------------------------------------------------------------------
__global__ __launch_bounds__(256) void bin_scatter_kernel(const int* __restrict__ src,
                                                          const int* __restrict__ dst,
                                                          const int* __restrict__ rel,
                                                          int* __restrict__ bcur,
                                                          unsigned* __restrict__ binned) {
    int t = blockIdx.y;
    int e = blockIdx.x * blockDim.x + threadIdx.x;
    if (e >= E_EDGES) return;
    size_t o = (size_t)t * E_EDGES + e;
    int d = dst[o];
    int pos = atomicAdd(&bcur[t * NB + (d >> 7)], 1);
    binned[(size_t)t * E_EDGES + pos] =
        (unsigned)src[o] | ((unsigned)rel[o] << 16) | ((unsigned)(d & 127) << 25);
}

// ---------------------------------------------------------------------------
// Pass B: per-bucket LDS counting sort by dst&127 -> sorted (coalesced write),
// and emit row_ptr for the bucket's 128 nodes.
// ---------------------------------------------------------------------------
__global__ __launch_bounds__(256) void bucket_sort_kernel(
        const unsigned* __restrict__ binned, const int* __restrict__ bhist,
        const int* __restrict__ boffs,
        unsigned* __restrict__ sorted, int* __restrict__ row_ptr) {
    __shared__ unsigned pay[1024];
    __shared__ unsigned ord[1024];
    __shared__ int hist[128], scn[128], cur[128];
    int b = blockIdx.x, t = blockIdx.y, tid = threadIdx.x;
    int base  = boffs[t * NB + b];
    int count = bhist[t * NB + b];

    for (int i = tid; i < count; i += 256)
        pay[i] = binned[(size_t)t * E_EDGES + base + i];
    if (tid < 128) hist[tid] = 0;
    __syncthreads();
    for (int i = tid; i < count; i += 256)
        atomicAdd(&hist[pay[i] >> 25], 1);
    __syncthreads();
    if (tid < 128) scn[tid] = hist[tid];
    __syncthreads();
    for (int off = 1; off < 128; off <<= 1) {
        int v = (tid < 128 && tid >= off) ? scn[tid - off] : 0;
        __syncthreads();
        if (tid < 128) scn[tid] += v;
        __syncthreads();
    }
    if (tid < 128) {
        int node = b * 128 + tid;
        if (node < N_ENT) row_ptr[t * (N_ENT + 1) + node + 1] = base + scn[tid];
        cur[tid] = scn[tid] - hist[tid];     // exclusive
    }
    __syncthreads();
    for (int i = tid; i < count; i += 256) {
        unsigned v = pay[i];
        int pos = atomicAdd(&cur[v >> 25], 1);
        ord[pos] = v & 0x01FFFFFFu;          // strip dstlow; keep src | rel<<16
    }
    __syncthreads();
    for (int i = tid; i < count; i += 256)
        sorted[(size_t)t * E_EDGES + base + i] = ord[i];
}

// ---------------------------------------------------------------------------
// Gather-mean in tangent space (R9 structure: wave per node, 4 edges/iter)
// M16[d] = mean over in-edges of (h_tan16[s] + emb_rel16[r])
// ---------------------------------------------------------------------------
__global__ __launch_bounds__(256) void gather_sum_kernel(
        const f16* __restrict__ h_tan16, const f16* __restrict__ emb_rel16,
        const int* __restrict__ row_ptr, const unsigned* __restrict__ sorted,
        f16* __restrict__ M16) {
    int wid  = (blockIdx.x * blockDim.x + threadIdx.x) >> 6;
    int lane = threadIdx.x & 63;
    if (wid >= N_ENT) return;

    const int cb8 = (lane & 15) * 8;
    int beg = row_ptr[wid], end = row_ptr[wid + 1];

    float acc[8];
    #pragma unroll
    for (int j = 0; j < 8; ++j) acc[j] = 0.f;

    for (int e = beg; e < end; e += 4) {
        int idx = e + (lane >> 4);
        bool valid = idx < end;
        unsigned v = sorted[valid ? idx : beg];
        int s = v & 0xFFFFu, r = v >> 16;
        const f16x8 hv = *reinterpret_cast<const f16x8*>(h_tan16   + s * D + cb8);
        const f16x8 rv = *reinterpret_cast<const f16x8*>(emb_rel16 + r * D + cb8);
        float m = valid ? 1.f : 0.f;
        #pragma unroll
        for (int j = 0; j < 8; ++j)
            acc[j] = fmaf(m, (float)hv[j] + (float)rv[j], acc[j]);
    }
    #pragma unroll
    for (int j = 0; j < 8; ++j) {
        acc[j] += __shfl_xor(acc[j], 16, 64);
        acc[j] += __shfl_xor(acc[j], 32, 64);
    }

    if (lane < 16) {
        float inv = 1.0f / fmaxf((float)(end - beg), 1.0f);
        f16x8 o;
        #pragma unroll
        for (int j = 0; j < 8; ++j) o[j] = (f16)(acc[j] * inv);
        *reinterpret_cast<f16x8*>(M16 + (size_t)wid * D + cb8) = o;
    }
}

// ---------------------------------------------------------------------------
// Fused GEMM + mix (R9 structure): P=M@wn, L=ht@wl, G=ht@wg; mix epilogue.
// ---------------------------------------------------------------------------
__global__ __launch_bounds__(256) void gemm_mix_kernel(
        const f16* __restrict__ M16, f16* __restrict__ h_tan16,
        float* __restrict__ h_tan, const f16* __restrict__ wpack,
        float* __restrict__ h_out, int last) {
    __shared__ f16 m_s[64 * 128];
    __shared__ f16 a_s[64 * 128];
    const int tid = threadIdx.x;
    const int rowBase = blockIdx.x * 64;

    {   // stage both tiles, XOR-swizzled (half-index ^ ((row&7)<<3))
        int r = tid >> 2, q = tid & 3;
        const float4* srcM = reinterpret_cast<const float4*>(M16     + (size_t)(rowBase + r) * D + q * 32);
        const float4* srcA = reinterpret_cast<const float4*>(h_tan16 + (size_t)(rowBase + r) * D + q * 32);
        #pragma unroll
        for (int i = 0; i < 4; ++i) {
            int hoff = (q * 32 + i * 8) ^ ((r & 7) << 3);
            *reinterpret_cast<float4*>(&m_s[r * 128 + hoff]) = srcM[i];
            *reinterpret_cast<float4*>(&a_s[r * 128 + hoff]) = srcA[i];
        }
    }
    __syncthreads();

    const int wave = tid >> 6, lane = tid & 63;
    const int arow = wave * 16 + (lane & 15);

    f16x8 afM[4], afH[4];
    #pragma unroll
    for (int ks = 0; ks < 4; ++ks) {
        int hoff = (ks * 32 + (lane >> 4) * 8) ^ ((arow & 7) << 3);
        afM[ks] = *reinterpret_cast<const f16x8*>(&m_s[arow * 128 + hoff]);
        afH[ks] = *reinterpret_cast<const f16x8*>(&a_s[arow * 128 + hoff]);
    }

    const int orow = rowBase + arow;
    const int colq = (lane >> 4) * 4;

    f32x4 mx[8];
    float ss = 0.f;

    #pragma unroll
    for (int nt = 0; nt < 8; ++nt) {
        f32x4 accP = {0.f, 0.f, 0.f, 0.f};
        f32x4 accL = {0.f, 0.f, 0.f, 0.f};
        f32x4 accG = {0.f, 0.f, 0.f, 0.f};
        #pragma unroll
        for (int ks = 0; ks < 4; ++ks) {
            const f16x8 wfN = *reinterpret_cast<const f16x8*>(wpack + ((((0 * 8 + nt) * 4 + ks) * 64 + lane) << 3));
            const f16x8 wfL = *reinterpret_cast<const f16x8*>(wpack + ((((1 * 8 + nt) * 4 + ks) * 64 + lane) << 3));
            const f16x8 wfG = *reinterpret_cast<const f16x8*>(wpack + ((((2 * 8 + nt) * 4 + ks) * 64 + lane) << 3));
            accP = __builtin_amdgcn_mfma_f32_16x16x32_f16(wfN, afM[ks], accP, 0, 0, 0);
            accL = __builtin_amdgcn_mfma_f32_16x16x32_f16(wfL, afH[ks], accL, 0, 0, 0);
            accG = __builtin_amdgcn_mfma_f32_16x16x32_f16(wfG, afH[ks], accG, 0, 0, 0);
        }
        const size_t cidx = (size_t)orow * D + nt * 16 + colq;
        f32x4 ht = *reinterpret_cast<const f32x4*>(h_tan + cidx);
        f32x4 m;
        #pragma unroll
        for (int i = 0; i < 4; ++i) {
            float o = accP[i] + accL[i];
            o = (o >= 0.f) ? o : RRELU_SLOPE * o;
            float g = 1.0f / (1.0f + expf(-accG[i]));
            m[i] = fmaf(g, o - ht[i], ht[i]);
            ss = fmaf(m[i], m[i], ss);
        }
        mx[nt] = m;
        if (!last) {
            *reinterpret_cast<f32x4*>(h_tan + cidx) = m;
            f16x4 m16 = {(f16)m[0], (f16)m[1], (f16)m[2], (f16)m[3]};
            *reinterpret_cast<f16x4*>(h_tan16 + cidx) = m16;
        }
    }

    if (last) {
        ss += __shfl_xor(ss, 16, 64);
        ss += __shfl_xor(ss, 32, 64);
        float n = fmaxf(sqrtf(ss), EPS_);
        float s = tanhf(SQC * n) / (SQC * n);
        #pragma unroll
        for (int nt = 0; nt < 8; ++nt) {
            const size_t cidx = (size_t)orow * D + nt * 16 + colq;
            f32x4 o = {mx[nt][0] * s, mx[nt][1] * s, mx[nt][2] * s, mx[nt][3] * s};
            *reinterpret_cast<f32x4*>(h_out + cidx) = o;
        }
    }
}

// ---------------------------------------------------------------------------
extern "C" void kernel_launch(void* const* d_in, const int* in_sizes, int n_in,
                              void* d_out, int out_size, void* d_ws, size_t ws_size,
                              hipStream_t stream) {
    const int*   src  = (const int*)d_in[0];
    const int*   dst  = (const int*)d_in[1];
    const int*   rel  = (const int*)d_in[2];
    const float* dyn  = (const float*)d_in[3];
    const float* erel = (const float*)d_in[4];
    const float* wn   = (const float*)d_in[5];
    const float* wl   = (const float*)d_in[6];
    const float* wg   = (const float*)d_in[7];
    float* h = (float*)d_out;

    const size_t ND = (size_t)N_ENT * D;
    char* p = (char*)d_ws;
    float* h_tan    = (float*)p;            p += ND * 4;
    f16*   h_tan16  = (f16*)p;              p += ND * 2;
    f16*   M16      = (f16*)p;              p += ND * 2;
    f16*   emb_rel16= (f16*)p;              p += (size_t)N_REL2 * D * 2;
    f16*   wpack    = (f16*)p;              p += (size_t)3 * D * D * 2;
    unsigned* sorted= (unsigned*)p;         p += (size_t)T_STEPS * E_EDGES * 4;
    unsigned* binned= (unsigned*)p;         p += (size_t)T_STEPS * E_EDGES * 4;
    int*   bhist    = (int*)p;              p += (size_t)T_STEPS * NB * 4;
    int*   boffs    = (int*)p;              p += (size_t)T_STEPS * NB * 4;
    int*   bcur     = (int*)p;              p += (size_t)T_STEPS * NB * 4;
    int*   row_ptr  = (int*)p;              p += (size_t)T_STEPS * (N_ENT + 1) * 4;

    const int nodeBlocks = (N_ENT * 64 + 255) / 256;           // 10000
    const int edgeB      = (E_EDGES + 255) / 256;              // 782
    const int chunkB     = (E_EDGES + 2047) / 2048;            // 98

    // --- binned CSR build (all 8 steps) ---
    hipMemsetAsync(bhist, 0, (size_t)T_STEPS * NB * sizeof(int), stream);
    bin_hist_kernel<<<dim3(chunkB, T_STEPS), 256, 0, stream>>>(dst, bhist);
    bin_scan_kernel<<<T_STEPS, 512, 0, stream>>>(bhist, boffs, bcur, row_ptr);
    bin_scatter_kernel<<<dim3(edgeB, T_STEPS), 256, 0, stream>>>(src, dst, rel, bcur, binned);
    bucket_sort_kernel<<<dim3(NB, T_STEPS), 256, 0, stream>>>(binned, bhist, boffs, sorted, row_ptr);

    // --- loop-invariant precompute ---
    cvt_rel_kernel<<<(N_REL2 * D + 255) / 256, 256, 0, stream>>>(erel, emb_rel16);
    cvtw_kernel<<<192, 256, 0, stream>>>(wn, wl, wg, wpack);
    logmap_kernel<<<nodeBlocks, 256, 0, stream>>>(dyn, h_tan, h_tan16);

    for (int t = 0; t < T_STEPS; ++t) {
        gather_sum_kernel<<<nodeBlocks, 256, 0, stream>>>(
            h_tan16, emb_rel16,
            row_ptr + t * (N_ENT + 1), sorted + (size_t)t * E_EDGES, M16);
        gemm_mix_kernel<<<N_ENT / 64, 256, 0, stream>>>(
            M16, h_tan16, h_tan, wpack, h, (t == T_STEPS - 1) ? 1 : 0);
    }
}

// Round 13
// 468.490 us; speedup vs baseline: 1.5565x; 1.5565x over previous
//
#include <hip/hip_runtime.h>
#include <hip/hip_bf16.h>
#include <math.h>

#define N_ENT   40000
#define N_REL2  480
#define D       128
#define T_STEPS 8
#define E_EDGES 200000
#define SQC     0.1f                 // sqrt(C), C = 0.01
#define RRELU_SLOPE 0.22916666666666666f
#define EPS_    1e-6f
#define NB      313                  // buckets = ceil(N_ENT/128), key = dst>>7
#define NCHUNK  98                   // ceil(E_EDGES/2048)

typedef _Float16 f16;
typedef _Float16 f16x8 __attribute__((ext_vector_type(8)));
typedef _Float16 f16x4 __attribute__((ext_vector_type(4)));
typedef _Float16 f16x2 __attribute__((ext_vector_type(2)));
typedef float    f32x4 __attribute__((ext_vector_type(4)));

// ---------------------------------------------------------------------------
__global__ __launch_bounds__(256) void cvt_rel_kernel(const float* __restrict__ emb_rel,
                                                      f16* __restrict__ emb_rel16) {
    int i = blockIdx.x * blockDim.x + threadIdx.x;
    if (i < N_REL2 * D) emb_rel16[i] = (f16)emb_rel[i];
}

// ---------------------------------------------------------------------------
// Wpack: fragment-layout fp16 pack of {wn,wl,wg}.
// ---------------------------------------------------------------------------
__global__ __launch_bounds__(256) void cvtw_kernel(const float* __restrict__ wn,
                                                   const float* __restrict__ wl,
                                                   const float* __restrict__ wg,
                                                   f16* __restrict__ wpack) {
    int idx = blockIdx.x * blockDim.x + threadIdx.x;   // 0 .. 49151
    int j    = idx & 7;
    int lane = (idx >> 3) & 63;
    int ks   = (idx >> 9) & 3;
    int nt   = (idx >> 11) & 7;
    int g    = idx >> 14;
    const float* W = (g == 0) ? wn : (g == 1) ? wl : wg;
    int k = ks * 32 + (lane >> 4) * 8 + j;
    int n = nt * 16 + (lane & 15);
    wpack[idx] = (f16)W[k * D + n];
}

// ---------------------------------------------------------------------------
// logmap0 of initial h: h_tan (fp32) + h_tan16 (fp16)
// ---------------------------------------------------------------------------
__global__ __launch_bounds__(256) void logmap_kernel(const float* __restrict__ h,
                                                     float* __restrict__ h_tan,
                                                     f16* __restrict__ h_tan16) {
    int wid  = (blockIdx.x * blockDim.x + threadIdx.x) >> 6;
    int lane = threadIdx.x & 63;
    if (wid >= N_ENT) return;
    int base = wid * D + lane * 2;
    float2 hv = *reinterpret_cast<const float2*>(h + base);
    float ss = hv.x * hv.x + hv.y * hv.y;
    #pragma unroll
    for (int off = 32; off >= 1; off >>= 1) ss += __shfl_xor(ss, off, 64);
    float n = fmaxf(sqrtf(ss), EPS_);
    float t = fminf(SQC * n, 1.0f - 1e-5f);
    float scale = atanhf(t) / (SQC * n);
    float ox = hv.x * scale, oy = hv.y * scale;
    *reinterpret_cast<float2*>(h_tan + base) = make_float2(ox, oy);
    f16x2 o16 = {(f16)ox, (f16)oy};
    *reinterpret_cast<f16x2*>(h_tan16 + base) = o16;
}

// ---------------------------------------------------------------------------
// Pass A1: per-chunk bucket histogram (LDS only, no global atomics)
// ---------------------------------------------------------------------------
__global__ __launch_bounds__(256) void chunk_hist_kernel(const int* __restrict__ dst,
                                                         int* __restrict__ chunk_cnt) {
    __shared__ int lh[NB];
    int t = blockIdx.y, tid = threadIdx.x, chunk = blockIdx.x;
    for (int j = tid; j < NB; j += 256) lh[j] = 0;
    __syncthreads();
    int base = chunk * 2048;
    #pragma unroll
    for (int c = 0; c < 8; ++c) {
        int e = base + c * 256 + tid;
        if (e < E_EDGES) atomicAdd(&lh[dst[(size_t)t * E_EDGES + e] >> 7], 1);
    }
    __syncthreads();
    for (int j = tid; j < NB; j += 256)
        chunk_cnt[(t * NCHUNK + chunk) * NB + j] = lh[j];
}

// ---------------------------------------------------------------------------
// Pass A2: per step — bucket totals (sum over chunks), exclusive bucket scan,
// and per-bucket running prefix over chunks -> chunk_base. row_ptr[0]=0.
// ---------------------------------------------------------------------------
__global__ __launch_bounds__(320) void bin_scan_kernel(const int* __restrict__ chunk_cnt,
                                                       int* __restrict__ bhist,
                                                       int* __restrict__ boffs,
                                                       int* __restrict__ chunk_base,
                                                       int* __restrict__ row_ptr) {
    __shared__ int s[320];
    int t = blockIdx.x, tid = threadIdx.x;
    int total = 0;
    if (tid < NB)
        for (int c = 0; c < NCHUNK; ++c)
            total += chunk_cnt[(t * NCHUNK + c) * NB + tid];
    s[tid] = total;
    __syncthreads();
    for (int off = 1; off < 320; off <<= 1) {
        int v = (tid >= off) ? s[tid - off] : 0;
        __syncthreads();
        s[tid] += v;
        __syncthreads();
    }
    if (tid < NB) {
        int excl = s[tid] - total;
        bhist[t * NB + tid] = total;
        boffs[t * NB + tid] = excl;
        int run = excl;
        for (int c = 0; c < NCHUNK; ++c) {
            chunk_base[(t * NCHUNK + c) * NB + tid] = run;
            run += chunk_cnt[(t * NCHUNK + c) * NB + tid];
        }
    }
    if (tid == 0) row_ptr[t * (N_ENT + 1)] = 0;
}

// ---------------------------------------------------------------------------
// Pass A3: scatter via LDS cursors seeded from chunk_base (no global atomics).
// payload = src | rel<<16 | (dst&127)<<25
// ---------------------------------------------------------------------------
__global__ __launch_bounds__(256) void bin_scatter_kernel(const int* __restrict__ src,
                                                          const int* __restrict__ dst,
                                                          const int* __restrict__ rel,
                                                          const int* __restrict__ chunk_base,
                                                          unsigned* __restrict__ binned) {
    __shared__ int cur[NB];
    int t = blockIdx.y, tid = threadIdx.x, chunk = blockIdx.x;
    for (int j = tid; j < NB; j += 256)
        cur[j] = chunk_base[(t * NCHUNK + chunk) * NB + j];
    __syncthreads();
    int base = chunk * 2048;
    #pragma unroll
    for (int c = 0; c < 8; ++c) {
        int e = base + c * 256 + tid;
        if (e < E_EDGES) {
            size_t o = (size_t)t * E_EDGES + e;
            int d = dst[o];
            int pos = atomicAdd(&cur[d >> 7], 1);    // LDS atomic
            binned[(size_t)t * E_EDGES + pos] =
                (unsigned)src[o] | ((unsigned)rel[o] << 16) | ((unsigned)(d & 127) << 25);
        }
    }
}

// ---------------------------------------------------------------------------
// Pass B: per-bucket LDS counting sort by dst&127 -> sorted (coalesced),
// and emit row_ptr for the bucket's 128 nodes. (verified in R12)
// ---------------------------------------------------------------------------
__global__ __launch_bounds__(256) void bucket_sort_kernel(
        const unsigned* __restrict__ binned, const int* __restrict__ bhist,
        const int* __restrict__ boffs,
        unsigned* __restrict__ sorted, int* __restrict__ row_ptr) {
    __shared__ unsigned pay[1024];
    __shared__ unsigned ord[1024];
    __shared__ int hist[128], scn[128], cur[128];
    int b = blockIdx.x, t = blockIdx.y, tid = threadIdx.x;
    int base  = boffs[t * NB + b];
    int count = bhist[t * NB + b];

    for (int i = tid; i < count; i += 256)
        pay[i] = binned[(size_t)t * E_EDGES + base + i];
    if (tid < 128) hist[tid] = 0;
    __syncthreads();
    for (int i = tid; i < count; i += 256)
        atomicAdd(&hist[pay[i] >> 25], 1);
    __syncthreads();
    if (tid < 128) scn[tid] = hist[tid];
    __syncthreads();
    for (int off = 1; off < 128; off <<= 1) {
        int v = (tid < 128 && tid >= off) ? scn[tid - off] : 0;
        __syncthreads();
        if (tid < 128) scn[tid] += v;
        __syncthreads();
    }
    if (tid < 128) {
        int node = b * 128 + tid;
        if (node < N_ENT) row_ptr[t * (N_ENT + 1) + node + 1] = base + scn[tid];
        cur[tid] = scn[tid] - hist[tid];     // exclusive
    }
    __syncthreads();
    for (int i = tid; i < count; i += 256) {
        unsigned v = pay[i];
        int pos = atomicAdd(&cur[v >> 25], 1);
        ord[pos] = v & 0x01FFFFFFu;          // strip dstlow; keep src | rel<<16
    }
    __syncthreads();
    for (int i = tid; i < count; i += 256)
        sorted[(size_t)t * E_EDGES + base + i] = ord[i];
}

// ---------------------------------------------------------------------------
// Gather-mean in tangent space (R9 structure: wave per node, 4 edges/iter)
// ---------------------------------------------------------------------------
__global__ __launch_bounds__(256) void gather_sum_kernel(
        const f16* __restrict__ h_tan16, const f16* __restrict__ emb_rel16,
        const int* __restrict__ row_ptr, const unsigned* __restrict__ sorted,
        f16* __restrict__ M16) {
    int wid  = (blockIdx.x * blockDim.x + threadIdx.x) >> 6;
    int lane = threadIdx.x & 63;
    if (wid >= N_ENT) return;

    const int cb8 = (lane & 15) * 8;
    int beg = row_ptr[wid], end = row_ptr[wid + 1];

    float acc[8];
    #pragma unroll
    for (int j = 0; j < 8; ++j) acc[j] = 0.f;

    for (int e = beg; e < end; e += 4) {
        int idx = e + (lane >> 4);
        bool valid = idx < end;
        unsigned v = sorted[valid ? idx : beg];
        int s = v & 0xFFFFu, r = v >> 16;
        const f16x8 hv = *reinterpret_cast<const f16x8*>(h_tan16   + s * D + cb8);
        const f16x8 rv = *reinterpret_cast<const f16x8*>(emb_rel16 + r * D + cb8);
        float m = valid ? 1.f : 0.f;
        #pragma unroll
        for (int j = 0; j < 8; ++j)
            acc[j] = fmaf(m, (float)hv[j] + (float)rv[j], acc[j]);
    }
    #pragma unroll
    for (int j = 0; j < 8; ++j) {
        acc[j] += __shfl_xor(acc[j], 16, 64);
        acc[j] += __shfl_xor(acc[j], 32, 64);
    }

    if (lane < 16) {
        float inv = 1.0f / fmaxf((float)(end - beg), 1.0f);
        f16x8 o;
        #pragma unroll
        for (int j = 0; j < 8; ++j) o[j] = (f16)(acc[j] * inv);
        *reinterpret_cast<f16x8*>(M16 + (size_t)wid * D + cb8) = o;
    }
}

// ---------------------------------------------------------------------------
// Fused GEMM + mix (R9 structure)
// ---------------------------------------------------------------------------
__global__ __launch_bounds__(256) void gemm_mix_kernel(
        const f16* __restrict__ M16, f16* __restrict__ h_tan16,
        float* __restrict__ h_tan, const f16* __restrict__ wpack,
        float* __restrict__ h_out, int last) {
    __shared__ f16 m_s[64 * 128];
    __shared__ f16 a_s[64 * 128];
    const int tid = threadIdx.x;
    const int rowBase = blockIdx.x * 64;

    {
        int r = tid >> 2, q = tid & 3;
        const float4* srcM = reinterpret_cast<const float4*>(M16     + (size_t)(rowBase + r) * D + q * 32);
        const float4* srcA = reinterpret_cast<const float4*>(h_tan16 + (size_t)(rowBase + r) * D + q * 32);
        #pragma unroll
        for (int i = 0; i < 4; ++i) {
            int hoff = (q * 32 + i * 8) ^ ((r & 7) << 3);
            *reinterpret_cast<float4*>(&m_s[r * 128 + hoff]) = srcM[i];
            *reinterpret_cast<float4*>(&a_s[r * 128 + hoff]) = srcA[i];
        }
    }
    __syncthreads();

    const int wave = tid >> 6, lane = tid & 63;
    const int arow = wave * 16 + (lane & 15);

    f16x8 afM[4], afH[4];
    #pragma unroll
    for (int ks = 0; ks < 4; ++ks) {
        int hoff = (ks * 32 + (lane >> 4) * 8) ^ ((arow & 7) << 3);
        afM[ks] = *reinterpret_cast<const f16x8*>(&m_s[arow * 128 + hoff]);
        afH[ks] = *reinterpret_cast<const f16x8*>(&a_s[arow * 128 + hoff]);
    }

    const int orow = rowBase + arow;
    const int colq = (lane >> 4) * 4;

    f32x4 mx[8];
    float ss = 0.f;

    #pragma unroll
    for (int nt = 0; nt < 8; ++nt) {
        f32x4 accP = {0.f, 0.f, 0.f, 0.f};
        f32x4 accL = {0.f, 0.f, 0.f, 0.f};
        f32x4 accG = {0.f, 0.f, 0.f, 0.f};
        #pragma unroll
        for (int ks = 0; ks < 4; ++ks) {
            const f16x8 wfN = *reinterpret_cast<const f16x8*>(wpack + ((((0 * 8 + nt) * 4 + ks) * 64 + lane) << 3));
            const f16x8 wfL = *reinterpret_cast<const f16x8*>(wpack + ((((1 * 8 + nt) * 4 + ks) * 64 + lane) << 3));
            const f16x8 wfG = *reinterpret_cast<const f16x8*>(wpack + ((((2 * 8 + nt) * 4 + ks) * 64 + lane) << 3));
            accP = __builtin_amdgcn_mfma_f32_16x16x32_f16(wfN, afM[ks], accP, 0, 0, 0);
            accL = __builtin_amdgcn_mfma_f32_16x16x32_f16(wfL, afH[ks], accL, 0, 0, 0);
            accG = __builtin_amdgcn_mfma_f32_16x16x32_f16(wfG, afH[ks], accG, 0, 0, 0);
        }
        const size_t cidx = (size_t)orow * D + nt * 16 + colq;
        f32x4 ht = *reinterpret_cast<const f32x4*>(h_tan + cidx);
        f32x4 m;
        #pragma unroll
        for (int i = 0; i < 4; ++i) {
            float o = accP[i] + accL[i];
            o = (o >= 0.f) ? o : RRELU_SLOPE * o;
            float g = 1.0f / (1.0f + expf(-accG[i]));
            m[i] = fmaf(g, o - ht[i], ht[i]);
            ss = fmaf(m[i], m[i], ss);
        }
        mx[nt] = m;
        if (!last) {
            *reinterpret_cast<f32x4*>(h_tan + cidx) = m;
            f16x4 m16 = {(f16)m[0], (f16)m[1], (f16)m[2], (f16)m[3]};
            *reinterpret_cast<f16x4*>(h_tan16 + cidx) = m16;
        }
    }

    if (last) {
        ss += __shfl_xor(ss, 16, 64);
        ss += __shfl_xor(ss, 32, 64);
        float n = fmaxf(sqrtf(ss), EPS_);
        float s = tanhf(SQC * n) / (SQC * n);
        #pragma unroll
        for (int nt = 0; nt < 8; ++nt) {
            const size_t cidx = (size_t)orow * D + nt * 16 + colq;
            f32x4 o = {mx[nt][0] * s, mx[nt][1] * s, mx[nt][2] * s, mx[nt][3] * s};
            *reinterpret_cast<f32x4*>(h_out + cidx) = o;
        }
    }
}

// ---------------------------------------------------------------------------
extern "C" void kernel_launch(void* const* d_in, const int* in_sizes, int n_in,
                              void* d_out, int out_size, void* d_ws, size_t ws_size,
                              hipStream_t stream) {
    const int*   src  = (const int*)d_in[0];
    const int*   dst  = (const int*)d_in[1];
    const int*   rel  = (const int*)d_in[2];
    const float* dyn  = (const float*)d_in[3];
    const float* erel = (const float*)d_in[4];
    const float* wn   = (const float*)d_in[5];
    const float* wl   = (const float*)d_in[6];
    const float* wg   = (const float*)d_in[7];
    float* h = (float*)d_out;

    const size_t ND = (size_t)N_ENT * D;
    char* p = (char*)d_ws;
    float* h_tan    = (float*)p;            p += ND * 4;
    f16*   h_tan16  = (f16*)p;              p += ND * 2;
    f16*   M16      = (f16*)p;              p += ND * 2;
    f16*   emb_rel16= (f16*)p;              p += (size_t)N_REL2 * D * 2;
    f16*   wpack    = (f16*)p;              p += (size_t)3 * D * D * 2;
    unsigned* sorted= (unsigned*)p;         p += (size_t)T_STEPS * E_EDGES * 4;
    unsigned* binned= (unsigned*)p;         p += (size_t)T_STEPS * E_EDGES * 4;
    int* chunk_cnt  = (int*)p;              p += (size_t)T_STEPS * NCHUNK * NB * 4;
    int* chunk_base = (int*)p;              p += (size_t)T_STEPS * NCHUNK * NB * 4;
    int*   bhist    = (int*)p;              p += (size_t)T_STEPS * NB * 4;
    int*   boffs    = (int*)p;              p += (size_t)T_STEPS * NB * 4;
    int*   row_ptr  = (int*)p;              p += (size_t)T_STEPS * (N_ENT + 1) * 4;

    const int nodeBlocks = (N_ENT * 64 + 255) / 256;           // 10000

    // --- binned CSR build, no global atomics ---
    chunk_hist_kernel<<<dim3(NCHUNK, T_STEPS), 256, 0, stream>>>(dst, chunk_cnt);
    bin_scan_kernel<<<T_STEPS, 320, 0, stream>>>(chunk_cnt, bhist, boffs, chunk_base, row_ptr);
    bin_scatter_kernel<<<dim3(NCHUNK, T_STEPS), 256, 0, stream>>>(src, dst, rel, chunk_base, binned);
    bucket_sort_kernel<<<dim3(NB, T_STEPS), 256, 0, stream>>>(binned, bhist, boffs, sorted, row_ptr);

    // --- loop-invariant precompute ---
    cvt_rel_kernel<<<(N_REL2 * D + 255) / 256, 256, 0, stream>>>(erel, emb_rel16);
    cvtw_kernel<<<192, 256, 0, stream>>>(wn, wl, wg, wpack);
    logmap_kernel<<<nodeBlocks, 256, 0, stream>>>(dyn, h_tan, h_tan16);

    for (int t = 0; t < T_STEPS; ++t) {
        gather_sum_kernel<<<nodeBlocks, 256, 0, stream>>>(
            h_tan16, emb_rel16,
            row_ptr + t * (N_ENT + 1), sorted + (size_t)t * E_EDGES, M16);
        gemm_mix_kernel<<<N_ENT / 64, 256, 0, stream>>>(
            M16, h_tan16, h_tan, wpack, h, (t == T_STEPS - 1) ? 1 : 0);
    }
}

// Round 14
// 446.409 us; speedup vs baseline: 1.6335x; 1.0495x over previous
//
#include <hip/hip_runtime.h>
#include <hip/hip_bf16.h>
#include <math.h>

#define N_ENT   40000
#define N_REL2  480
#define D       128
#define T_STEPS 8
#define E_EDGES 200000
#define SQC     0.1f                 // sqrt(C), C = 0.01
#define RRELU_SLOPE 0.22916666666666666f
#define EPS_    1e-6f
#define NB      313                  // buckets = ceil(N_ENT/128), key = dst>>7
#define NCHUNK  98                   // ceil(E_EDGES/2048)

typedef _Float16 f16;
typedef _Float16 f16x8 __attribute__((ext_vector_type(8)));
typedef _Float16 f16x4 __attribute__((ext_vector_type(4)));
typedef _Float16 f16x2 __attribute__((ext_vector_type(2)));
typedef float    f32x4 __attribute__((ext_vector_type(4)));

// ---------------------------------------------------------------------------
__global__ __launch_bounds__(256) void cvt_rel_kernel(const float* __restrict__ emb_rel,
                                                      f16* __restrict__ emb_rel16) {
    int i = blockIdx.x * blockDim.x + threadIdx.x;
    if (i < N_REL2 * D) emb_rel16[i] = (f16)emb_rel[i];
}

// ---------------------------------------------------------------------------
// Wpack: fragment-layout fp16 pack of {wn,wl,wg}.
// ---------------------------------------------------------------------------
__global__ __launch_bounds__(256) void cvtw_kernel(const float* __restrict__ wn,
                                                   const float* __restrict__ wl,
                                                   const float* __restrict__ wg,
                                                   f16* __restrict__ wpack) {
    int idx = blockIdx.x * blockDim.x + threadIdx.x;   // 0 .. 49151
    int j    = idx & 7;
    int lane = (idx >> 3) & 63;
    int ks   = (idx >> 9) & 3;
    int nt   = (idx >> 11) & 7;
    int g    = idx >> 14;
    const float* W = (g == 0) ? wn : (g == 1) ? wl : wg;
    int k = ks * 32 + (lane >> 4) * 8 + j;
    int n = nt * 16 + (lane & 15);
    wpack[idx] = (f16)W[k * D + n];
}

// ---------------------------------------------------------------------------
// logmap0 of initial h -> fp16 state only
// ---------------------------------------------------------------------------
__global__ __launch_bounds__(256) void logmap_kernel(const float* __restrict__ h,
                                                     f16* __restrict__ h_tan16) {
    int wid  = (blockIdx.x * blockDim.x + threadIdx.x) >> 6;
    int lane = threadIdx.x & 63;
    if (wid >= N_ENT) return;
    int base = wid * D + lane * 2;
    float2 hv = *reinterpret_cast<const float2*>(h + base);
    float ss = hv.x * hv.x + hv.y * hv.y;
    #pragma unroll
    for (int off = 32; off >= 1; off >>= 1) ss += __shfl_xor(ss, off, 64);
    float n = fmaxf(sqrtf(ss), EPS_);
    float t = fminf(SQC * n, 1.0f - 1e-5f);
    float scale = atanhf(t) / (SQC * n);
    f16x2 o16 = {(f16)(hv.x * scale), (f16)(hv.y * scale)};
    *reinterpret_cast<f16x2*>(h_tan16 + base) = o16;
}

// ---------------------------------------------------------------------------
// Pass A1: per-chunk bucket histogram (LDS only, no global atomics)
// ---------------------------------------------------------------------------
__global__ __launch_bounds__(256) void chunk_hist_kernel(const int* __restrict__ dst,
                                                         int* __restrict__ chunk_cnt) {
    __shared__ int lh[NB];
    int t = blockIdx.y, tid = threadIdx.x, chunk = blockIdx.x;
    for (int j = tid; j < NB; j += 256) lh[j] = 0;
    __syncthreads();
    int base = chunk * 2048;
    #pragma unroll
    for (int c = 0; c < 8; ++c) {
        int e = base + c * 256 + tid;
        if (e < E_EDGES) atomicAdd(&lh[dst[(size_t)t * E_EDGES + e] >> 7], 1);
    }
    __syncthreads();
    for (int j = tid; j < NB; j += 256)
        chunk_cnt[(t * NCHUNK + chunk) * NB + j] = lh[j];
}

// ---------------------------------------------------------------------------
// Pass A2: bucket totals -> exclusive scan -> per-chunk bases. row_ptr[0]=0.
// ---------------------------------------------------------------------------
__global__ __launch_bounds__(320) void bin_scan_kernel(const int* __restrict__ chunk_cnt,
                                                       int* __restrict__ bhist,
                                                       int* __restrict__ boffs,
                                                       int* __restrict__ chunk_base,
                                                       int* __restrict__ row_ptr) {
    __shared__ int s[320];
    int t = blockIdx.x, tid = threadIdx.x;
    int total = 0;
    if (tid < NB)
        for (int c = 0; c < NCHUNK; ++c)
            total += chunk_cnt[(t * NCHUNK + c) * NB + tid];
    s[tid] = total;
    __syncthreads();
    for (int off = 1; off < 320; off <<= 1) {
        int v = (tid >= off) ? s[tid - off] : 0;
        __syncthreads();
        s[tid] += v;
        __syncthreads();
    }
    if (tid < NB) {
        int excl = s[tid] - total;
        bhist[t * NB + tid] = total;
        boffs[t * NB + tid] = excl;
        int run = excl;
        for (int c = 0; c < NCHUNK; ++c) {
            chunk_base[(t * NCHUNK + c) * NB + tid] = run;
            run += chunk_cnt[(t * NCHUNK + c) * NB + tid];
        }
    }
    if (tid == 0) row_ptr[t * (N_ENT + 1)] = 0;
}

// ---------------------------------------------------------------------------
// Pass A3: scatter via LDS cursors seeded from chunk_base (no global atomics).
// payload = src | rel<<16 | (dst&127)<<25
// ---------------------------------------------------------------------------
__global__ __launch_bounds__(256) void bin_scatter_kernel(const int* __restrict__ src,
                                                          const int* __restrict__ dst,
                                                          const int* __restrict__ rel,
                                                          const int* __restrict__ chunk_base,
                                                          unsigned* __restrict__ binned) {
    __shared__ int cur[NB];
    int t = blockIdx.y, tid = threadIdx.x, chunk = blockIdx.x;
    for (int j = tid; j < NB; j += 256)
        cur[j] = chunk_base[(t * NCHUNK + chunk) * NB + j];
    __syncthreads();
    int base = chunk * 2048;
    #pragma unroll
    for (int c = 0; c < 8; ++c) {
        int e = base + c * 256 + tid;
        if (e < E_EDGES) {
            size_t o = (size_t)t * E_EDGES + e;
            int d = dst[o];
            int pos = atomicAdd(&cur[d >> 7], 1);    // LDS atomic
            binned[(size_t)t * E_EDGES + pos] =
                (unsigned)src[o] | ((unsigned)rel[o] << 16) | ((unsigned)(d & 127) << 25);
        }
    }
}

// ---------------------------------------------------------------------------
// Pass B: per-bucket LDS counting sort by dst&127 -> sorted (coalesced),
// and emit row_ptr for the bucket's 128 nodes.
// ---------------------------------------------------------------------------
__global__ __launch_bounds__(256) void bucket_sort_kernel(
        const unsigned* __restrict__ binned, const int* __restrict__ bhist,
        const int* __restrict__ boffs,
        unsigned* __restrict__ sorted, int* __restrict__ row_ptr) {
    __shared__ unsigned pay[1024];
    __shared__ unsigned ord[1024];
    __shared__ int hist[128], scn[128], cur[128];
    int b = blockIdx.x, t = blockIdx.y, tid = threadIdx.x;
    int base  = boffs[t * NB + b];
    int count = bhist[t * NB + b];

    for (int i = tid; i < count; i += 256)
        pay[i] = binned[(size_t)t * E_EDGES + base + i];
    if (tid < 128) hist[tid] = 0;
    __syncthreads();
    for (int i = tid; i < count; i += 256)
        atomicAdd(&hist[pay[i] >> 25], 1);
    __syncthreads();
    if (tid < 128) scn[tid] = hist[tid];
    __syncthreads();
    for (int off = 1; off < 128; off <<= 1) {
        int v = (tid < 128 && tid >= off) ? scn[tid - off] : 0;
        __syncthreads();
        if (tid < 128) scn[tid] += v;
        __syncthreads();
    }
    if (tid < 128) {
        int node = b * 128 + tid;
        if (node < N_ENT) row_ptr[t * (N_ENT + 1) + node + 1] = base + scn[tid];
        cur[tid] = scn[tid] - hist[tid];     // exclusive
    }
    __syncthreads();
    for (int i = tid; i < count; i += 256) {
        unsigned v = pay[i];
        int pos = atomicAdd(&cur[v >> 25], 1);
        ord[pos] = v & 0x01FFFFFFu;          // strip dstlow; keep src | rel<<16
    }
    __syncthreads();
    for (int i = tid; i < count; i += 256)
        sorted[(size_t)t * E_EDGES + base + i] = ord[i];
}

// ---------------------------------------------------------------------------
// Gather-mean in tangent space (wave per node, 4 edges/iter, f16x8 loads)
// ---------------------------------------------------------------------------
__global__ __launch_bounds__(256) void gather_sum_kernel(
        const f16* __restrict__ h_tan16, const f16* __restrict__ emb_rel16,
        const int* __restrict__ row_ptr, const unsigned* __restrict__ sorted,
        f16* __restrict__ M16) {
    int wid  = (blockIdx.x * blockDim.x + threadIdx.x) >> 6;
    int lane = threadIdx.x & 63;
    if (wid >= N_ENT) return;

    const int cb8 = (lane & 15) * 8;
    int beg = row_ptr[wid], end = row_ptr[wid + 1];

    float acc[8];
    #pragma unroll
    for (int j = 0; j < 8; ++j) acc[j] = 0.f;

    for (int e = beg; e < end; e += 4) {
        int idx = e + (lane >> 4);
        bool valid = idx < end;
        unsigned v = sorted[valid ? idx : beg];
        int s = v & 0xFFFFu, r = v >> 16;
        const f16x8 hv = *reinterpret_cast<const f16x8*>(h_tan16   + s * D + cb8);
        const f16x8 rv = *reinterpret_cast<const f16x8*>(emb_rel16 + r * D + cb8);
        float m = valid ? 1.f : 0.f;
        #pragma unroll
        for (int j = 0; j < 8; ++j)
            acc[j] = fmaf(m, (float)hv[j] + (float)rv[j], acc[j]);
    }
    #pragma unroll
    for (int j = 0; j < 8; ++j) {
        acc[j] += __shfl_xor(acc[j], 16, 64);
        acc[j] += __shfl_xor(acc[j], 32, 64);
    }

    if (lane < 16) {
        float inv = 1.0f / fmaxf((float)(end - beg), 1.0f);
        f16x8 o;
        #pragma unroll
        for (int j = 0; j < 8; ++j) o[j] = (f16)(acc[j] * inv);
        *reinterpret_cast<f16x8*>(M16 + (size_t)wid * D + cb8) = o;
    }
}

// ---------------------------------------------------------------------------
// Fused GEMM + mix, fp16-only state. ht for the mix is read back from the
// staged a_s LDS tile (same values the MFMA consumes) — no fp32 state buffer.
// ---------------------------------------------------------------------------
__global__ __launch_bounds__(256) void gemm_mix_kernel(
        const f16* __restrict__ M16, f16* __restrict__ h_tan16,
        const f16* __restrict__ wpack,
        float* __restrict__ h_out, int last) {
    __shared__ f16 m_s[64 * 128];
    __shared__ f16 a_s[64 * 128];
    const int tid = threadIdx.x;
    const int rowBase = blockIdx.x * 64;

    {   // stage both tiles, XOR-swizzled (half-index ^ ((row&7)<<3))
        int r = tid >> 2, q = tid & 3;
        const float4* srcM = reinterpret_cast<const float4*>(M16     + (size_t)(rowBase + r) * D + q * 32);
        const float4* srcA = reinterpret_cast<const float4*>(h_tan16 + (size_t)(rowBase + r) * D + q * 32);
        #pragma unroll
        for (int i = 0; i < 4; ++i) {
            int hoff = (q * 32 + i * 8) ^ ((r & 7) << 3);
            *reinterpret_cast<float4*>(&m_s[r * 128 + hoff]) = srcM[i];
            *reinterpret_cast<float4*>(&a_s[r * 128 + hoff]) = srcA[i];
        }
    }
    __syncthreads();

    const int wave = tid >> 6, lane = tid & 63;
    const int arow = wave * 16 + (lane & 15);

    f16x8 afM[4], afH[4];
    #pragma unroll
    for (int ks = 0; ks < 4; ++ks) {
        int hoff = (ks * 32 + (lane >> 4) * 8) ^ ((arow & 7) << 3);
        afM[ks] = *reinterpret_cast<const f16x8*>(&m_s[arow * 128 + hoff]);
        afH[ks] = *reinterpret_cast<const f16x8*>(&a_s[arow * 128 + hoff]);
    }

    const int orow = rowBase + arow;
    const int colq = (lane >> 4) * 4;
    const int swz  = (arow & 7) << 3;

    f32x4 mx[8];
    float ss = 0.f;

    #pragma unroll
    for (int nt = 0; nt < 8; ++nt) {
        f32x4 accP = {0.f, 0.f, 0.f, 0.f};
        f32x4 accL = {0.f, 0.f, 0.f, 0.f};
        f32x4 accG = {0.f, 0.f, 0.f, 0.f};
        #pragma unroll
        for (int ks = 0; ks < 4; ++ks) {
            const f16x8 wfN = *reinterpret_cast<const f16x8*>(wpack + ((((0 * 8 + nt) * 4 + ks) * 64 + lane) << 3));
            const f16x8 wfL = *reinterpret_cast<const f16x8*>(wpack + ((((1 * 8 + nt) * 4 + ks) * 64 + lane) << 3));
            const f16x8 wfG = *reinterpret_cast<const f16x8*>(wpack + ((((2 * 8 + nt) * 4 + ks) * 64 + lane) << 3));
            accP = __builtin_amdgcn_mfma_f32_16x16x32_f16(wfN, afM[ks], accP, 0, 0, 0);
            accL = __builtin_amdgcn_mfma_f32_16x16x32_f16(wfL, afH[ks], accL, 0, 0, 0);
            accG = __builtin_amdgcn_mfma_f32_16x16x32_f16(wfG, afH[ks], accG, 0, 0, 0);
        }
        // ht from the staged LDS tile (fp16 state), C-layout col = nt*16+colq
        int hcol = nt * 16 + colq;                   // %8 in {0,4}; XOR hits bits>=3
        f16x4 htv = *reinterpret_cast<const f16x4*>(&a_s[arow * 128 + (hcol ^ swz)]);
        const size_t cidx = (size_t)orow * D + hcol;
        f32x4 m;
        #pragma unroll
        for (int i = 0; i < 4; ++i) {
            float o = accP[i] + accL[i];
            o = (o >= 0.f) ? o : RRELU_SLOPE * o;
            float g = 1.0f / (1.0f + expf(-accG[i]));
            float ht = (float)htv[i];
            m[i] = fmaf(g, o - ht, ht);
            ss = fmaf(m[i], m[i], ss);
        }
        mx[nt] = m;
        if (!last) {
            f16x4 m16 = {(f16)m[0], (f16)m[1], (f16)m[2], (f16)m[3]};
            *reinterpret_cast<f16x4*>(h_tan16 + cidx) = m16;
        }
    }

    if (last) {
        ss += __shfl_xor(ss, 16, 64);
        ss += __shfl_xor(ss, 32, 64);
        float n = fmaxf(sqrtf(ss), EPS_);
        float s = tanhf(SQC * n) / (SQC * n);
        #pragma unroll
        for (int nt = 0; nt < 8; ++nt) {
            const size_t cidx = (size_t)orow * D + nt * 16 + colq;
            f32x4 o = {mx[nt][0] * s, mx[nt][1] * s, mx[nt][2] * s, mx[nt][3] * s};
            *reinterpret_cast<f32x4*>(h_out + cidx) = o;
        }
    }
}

// ---------------------------------------------------------------------------
extern "C" void kernel_launch(void* const* d_in, const int* in_sizes, int n_in,
                              void* d_out, int out_size, void* d_ws, size_t ws_size,
                              hipStream_t stream) {
    const int*   src  = (const int*)d_in[0];
    const int*   dst  = (const int*)d_in[1];
    const int*   rel  = (const int*)d_in[2];
    const float* dyn  = (const float*)d_in[3];
    const float* erel = (const float*)d_in[4];
    const float* wn   = (const float*)d_in[5];
    const float* wl   = (const float*)d_in[6];
    const float* wg   = (const float*)d_in[7];
    float* h = (float*)d_out;

    const size_t ND = (size_t)N_ENT * D;
    char* p = (char*)d_ws;
    f16*   h_tan16  = (f16*)p;              p += ND * 2;
    f16*   M16      = (f16*)p;              p += ND * 2;
    f16*   emb_rel16= (f16*)p;              p += (size_t)N_REL2 * D * 2;
    f16*   wpack    = (f16*)p;              p += (size_t)3 * D * D * 2;
    unsigned* sorted= (unsigned*)p;         p += (size_t)T_STEPS * E_EDGES * 4;
    unsigned* binned= (unsigned*)p;         p += (size_t)T_STEPS * E_EDGES * 4;
    int* chunk_cnt  = (int*)p;              p += (size_t)T_STEPS * NCHUNK * NB * 4;
    int* chunk_base = (int*)p;              p += (size_t)T_STEPS * NCHUNK * NB * 4;
    int*   bhist    = (int*)p;              p += (size_t)T_STEPS * NB * 4;
    int*   boffs    = (int*)p;              p += (size_t)T_STEPS * NB * 4;
    int*   row_ptr  = (int*)p;              p += (size_t)T_STEPS * (N_ENT + 1) * 4;

    const int nodeBlocks = (N_ENT * 64 + 255) / 256;           // 10000

    // --- binned CSR build, no global atomics ---
    chunk_hist_kernel<<<dim3(NCHUNK, T_STEPS), 256, 0, stream>>>(dst, chunk_cnt);
    bin_scan_kernel<<<T_STEPS, 320, 0, stream>>>(chunk_cnt, bhist, boffs, chunk_base, row_ptr);
    bin_scatter_kernel<<<dim3(NCHUNK, T_STEPS), 256, 0, stream>>>(src, dst, rel, chunk_base, binned);
    bucket_sort_kernel<<<dim3(NB, T_STEPS), 256, 0, stream>>>(binned, bhist, boffs, sorted, row_ptr);

    // --- loop-invariant precompute ---
    cvt_rel_kernel<<<(N_REL2 * D + 255) / 256, 256, 0, stream>>>(erel, emb_rel16);
    cvtw_kernel<<<192, 256, 0, stream>>>(wn, wl, wg, wpack);
    logmap_kernel<<<nodeBlocks, 256, 0, stream>>>(dyn, h_tan16);

    for (int t = 0; t < T_STEPS; ++t) {
        gather_sum_kernel<<<nodeBlocks, 256, 0, stream>>>(
            h_tan16, emb_rel16,
            row_ptr + t * (N_ENT + 1), sorted + (size_t)t * E_EDGES, M16);
        gemm_mix_kernel<<<N_ENT / 64, 256, 0, stream>>>(
            M16, h_tan16, wpack, h, (t == T_STEPS - 1) ? 1 : 0);
    }
}